// Round 2
// baseline (595.769 us; speedup 1.0000x reference)
//
#include <hip/hip_runtime.h>

typedef unsigned short u16;
typedef unsigned int   u32;
typedef short bf16x8 __attribute__((ext_vector_type(8)));
typedef float f32x4  __attribute__((ext_vector_type(4)));

#define HID   512
#define NT    64            // columns per workgroup
#define NCOL  65536
#define PADC  520           // LDS column stride (elements): +8 el pad -> 4-bank shift
#define MAT_ELEMS (512 * 512)
#define FLAG_OFF  (8 * MAT_ELEMS)   // u16 elements before flag word (4 MiB bytes)

__device__ __forceinline__ float bf2f(u16 v) {
  union { u32 u; float f; } t; t.u = ((u32)v) << 16; return t.f;
}
__device__ __forceinline__ u16 f2bf(float f) {
  union { float f; u32 u; } t; t.f = f;
  u32 r = t.u + 0x7fffu + ((t.u >> 16) & 1u);   // round-to-nearest-even
  return (u16)(r >> 16);
}
// flag-aware scalar load: isbf ? bf16[i] : f32[i]
__device__ __forceinline__ float ldv(const void* p, int i, int isbf) {
  return isbf ? bf2f(((const u16*)p)[i]) : ((const float*)p)[i];
}
// tanh(x) = 1 - 2/(exp(2x)+1), exp via v_exp_f32 (exp2)
__device__ __forceinline__ float tanh_fast(float x) {
  float e = __builtin_amdgcn_exp2f(x * 2.8853900817779268f); // 2*log2(e)
  return 1.0f - 2.0f * __builtin_amdgcn_rcpf(e + 1.0f);
}

// ---------------- dtype sniff ----------------
// bf16 data: nearly all u16s have plausible bf16 exponents. fp32 data: only the
// high halves do (~58% total). Writes 1 (bf16) / 0 (fp32) to *flag.
__global__ void sniff_kernel(const u16* x, u32* flag) {
  if (threadIdx.x == 0 && blockIdx.x == 0) {
    int cnt = 0;
    for (int i = 0; i < 256; i++) {
      u32 e = (x[i] >> 7) & 0xFFu;
      if (e == 0u || (e >= 100u && e <= 140u)) cnt++;
    }
    *flag = (cnt >= 220) ? 1u : 0u;
  }
}

// ---------------- weight swizzle pre-pass ----------------
// dst layout per matrix: tile = kb*32 + rt  (kb=k/32, rt=row/16), 512 bf16 per tile,
// element (lane, j) at tile*512 + lane*8 + j  where row = rt*16 + (lane&15),
// k = kb*32 + (lane>>4)*8 + j  -> A-fragment load is lane*16B, fully coalesced.
struct SwzArgs { const void* src[8]; u16* dst; const u32* flag; };

__global__ void swizzle_kernel(SwzArgs a) {
  const int isbf = (int)*a.flag;
  int t = blockIdx.x * 256 + threadIdx.x;       // 262144 threads total
  int m    = t >> 15;                            // matrix 0..7
  int rem  = t & 32767;
  int tile = rem >> 6;                           // 0..511
  int lane = rem & 63;
  int kb = tile >> 5, rt = tile & 31;
  int row = rt * 16 + (lane & 15);
  int k   = kb * 32 + (lane >> 4) * 8;
  u16 tmp[8];
  if (isbf) {
    const u16* s = (const u16*)a.src[m] + row * 512 + k;
#pragma unroll
    for (int j = 0; j < 8; j++) tmp[j] = s[j];
  } else {
    const float* s = (const float*)a.src[m] + row * 512 + k;
#pragma unroll
    for (int j = 0; j < 8; j++) tmp[j] = f2bf(s[j]);
  }
  uint4* d = (uint4*)(a.dst + (size_t)m * MAT_ELEMS + (size_t)tile * 512 + lane * 8);
  *d = *(const uint4*)tmp;
}

// ---------------- fused network kernel ----------------
struct KArgs {
  const void* x;  const void* W1; const void* b1;
  const void* U[8];   // Uz1,Ug1,Ur1,Uh1,Uz2,Ug2,Ur2,Uh2
  const void* Bv[8];  // bz1,bg1,br1,bh1,bz2,bg2,br2,bh2
  const void* Wout; const void* bout;
  const u16* ws;      // swizzled Wz1,Wg1,Wr1,Wh1,Wz2,Wg2,Wr2,Wh2 (bf16)
  const u32* flag;
  void* out;
};

// acc init with U@x + b restricted to this wave's (r,c) footprint
__device__ __forceinline__ void init_acc(f32x4 acc[4][4],
    const void* __restrict__ U, const void* __restrict__ bias,
    const float* xs, int wave, int l15, int quad, int isbf)
{
#pragma unroll
  for (int rt = 0; rt < 4; rt++) {
#pragma unroll
    for (int i = 0; i < 4; i++) {
      int r = wave * 64 + rt * 16 + quad * 4 + i;
      float u0 = ldv(U, r * 3 + 0, isbf);
      float u1 = ldv(U, r * 3 + 1, isbf);
      float u2 = ldv(U, r * 3 + 2, isbf);
      float bb = ldv(bias, r, isbf);
#pragma unroll
      for (int ct = 0; ct < 4; ct++) {
        int c = ct * 16 + l15;
        acc[rt][ct][i] = u0 * xs[c] + u1 * xs[NT + c] + u2 * xs[2 * NT + c] + bb;
      }
    }
  }
}

// 512(M-slab per wave:64) x 512(K) x 64(N) GEMM step: A from swizzled global,
// B from LDS (column-major padded). Manual 1-deep A prefetch.
__device__ __forceinline__ void gemm64(f32x4 acc[4][4],
    const u16* __restrict__ wmat, const u16* ldsB, int wave, int lane, int l15, int quad)
{
  const u16* abase = wmat + (size_t)(wave * 4) * 512 + lane * 8;
  const u16* bbase = ldsB + l15 * PADC + quad * 8;
  bf16x8 a[4];
#pragma unroll
  for (int i = 0; i < 4; i++) a[i] = *(const bf16x8*)(abase + i * 512);
#pragma unroll
  for (int kb = 0; kb < 16; kb++) {
    bf16x8 b[4];
#pragma unroll
    for (int i = 0; i < 4; i++)
      b[i] = *(const bf16x8*)(bbase + kb * 32 + i * 16 * PADC);
    bf16x8 a2[4];
    if (kb < 15) {
#pragma unroll
      for (int i = 0; i < 4; i++)
        a2[i] = *(const bf16x8*)(abase + (size_t)(kb + 1) * 32 * 512 + i * 512);
    }
#pragma unroll
    for (int rt = 0; rt < 4; rt++)
#pragma unroll
      for (int ct = 0; ct < 4; ct++)
        acc[rt][ct] = __builtin_amdgcn_mfma_f32_16x16x32_bf16(a[rt], b[ct], acc[rt][ct], 0, 0, 0);
    if (kb < 15) {
#pragma unroll
      for (int i = 0; i < 4; i++) a[i] = a2[i];
    }
  }
}

__global__ __launch_bounds__(512, 2) void pdenet_kernel(KArgs ka) {
  __shared__ __align__(16) u16 ldsS[NT * PADC];   // current hidden state S (col-major)
  __shared__ __align__(16) u16 ldsR[NT * PADC];   // S*R buffer
  __shared__ float xs[3 * NT];

  const int isbf = (int)*ka.flag;
  const int tid  = threadIdx.x;
  const int wave = tid >> 6;
  const int lane = tid & 63;
  const int l15  = lane & 15;
  const int quad = lane >> 4;
  const int c0   = blockIdx.x * NT;

  if (tid < 3 * NT)
    xs[tid] = ldv(ka.x, (tid >> 6) * NCOL + c0 + (tid & 63), isbf);
  __syncthreads();

  // S1 = tanh(W1@x + b1): thread = row, iterate 64 columns
  {
    int r = tid;
    float w0 = ldv(ka.W1, r * 3 + 0, isbf);
    float w1 = ldv(ka.W1, r * 3 + 1, isbf);
    float w2 = ldv(ka.W1, r * 3 + 2, isbf);
    float bb = ldv(ka.b1, r, isbf);
#pragma unroll 4
    for (int c = 0; c < NT; c++) {
      float s = tanh_fast(w0 * xs[c] + w1 * xs[NT + c] + w2 * xs[2 * NT + c] + bb);
      ldsS[c * PADC + r] = f2bf(s);
    }
  }
  __syncthreads();

  u32 zpk[4][4][2], gpk[4][4][2];   // tanh'd Z,G held packed-bf16 in registers

#pragma unroll
  for (int layer = 0; layer < 2; layer++) {
    const int g0 = layer * 4;

    // ---- Z = tanh(Uz@x + Wz@S + bz) -> registers ----
    {
      f32x4 acc[4][4];
      init_acc(acc, ka.U[g0 + 0], ka.Bv[g0 + 0], xs, wave, l15, quad, isbf);
      gemm64(acc, ka.ws + (size_t)(g0 + 0) * MAT_ELEMS, ldsS, wave, lane, l15, quad);
#pragma unroll
      for (int rt = 0; rt < 4; rt++)
#pragma unroll
        for (int ct = 0; ct < 4; ct++) {
          u16 t0 = f2bf(tanh_fast(acc[rt][ct][0]));
          u16 t1 = f2bf(tanh_fast(acc[rt][ct][1]));
          u16 t2 = f2bf(tanh_fast(acc[rt][ct][2]));
          u16 t3 = f2bf(tanh_fast(acc[rt][ct][3]));
          zpk[rt][ct][0] = (u32)t0 | ((u32)t1 << 16);
          zpk[rt][ct][1] = (u32)t2 | ((u32)t3 << 16);
        }
    }
    // ---- G ----
    {
      f32x4 acc[4][4];
      init_acc(acc, ka.U[g0 + 1], ka.Bv[g0 + 1], xs, wave, l15, quad, isbf);
      gemm64(acc, ka.ws + (size_t)(g0 + 1) * MAT_ELEMS, ldsS, wave, lane, l15, quad);
#pragma unroll
      for (int rt = 0; rt < 4; rt++)
#pragma unroll
        for (int ct = 0; ct < 4; ct++) {
          u16 t0 = f2bf(tanh_fast(acc[rt][ct][0]));
          u16 t1 = f2bf(tanh_fast(acc[rt][ct][1]));
          u16 t2 = f2bf(tanh_fast(acc[rt][ct][2]));
          u16 t3 = f2bf(tanh_fast(acc[rt][ct][3]));
          gpk[rt][ct][0] = (u32)t0 | ((u32)t1 << 16);
          gpk[rt][ct][1] = (u32)t2 | ((u32)t3 << 16);
        }
    }
    // ---- R, then SR = S*R -> ldsR ----
    {
      f32x4 acc[4][4];
      init_acc(acc, ka.U[g0 + 2], ka.Bv[g0 + 2], xs, wave, l15, quad, isbf);
      gemm64(acc, ka.ws + (size_t)(g0 + 2) * MAT_ELEMS, ldsS, wave, lane, l15, quad);
#pragma unroll
      for (int rt = 0; rt < 4; rt++)
#pragma unroll
        for (int ct = 0; ct < 4; ct++) {
          int c  = ct * 16 + l15;
          int rb = wave * 64 + rt * 16 + quad * 4;
#pragma unroll
          for (int i = 0; i < 4; i++) {
            float rv = tanh_fast(acc[rt][ct][i]);
            float sv = bf2f(ldsS[c * PADC + rb + i]);
            ldsR[c * PADC + rb + i] = f2bf(sv * rv);
          }
        }
    }
    __syncthreads();   // publish SR for all waves
    // ---- H = tanh(Uh@x + Wh@SR + bh); S_next = (1-G)*H + Z*S -> ldsS ----
    {
      f32x4 acc[4][4];
      init_acc(acc, ka.U[g0 + 3], ka.Bv[g0 + 3], xs, wave, l15, quad, isbf);
      gemm64(acc, ka.ws + (size_t)(g0 + 3) * MAT_ELEMS, ldsR, wave, lane, l15, quad);
#pragma unroll
      for (int rt = 0; rt < 4; rt++)
#pragma unroll
        for (int ct = 0; ct < 4; ct++) {
          int c  = ct * 16 + l15;
          int rb = wave * 64 + rt * 16 + quad * 4;
#pragma unroll
          for (int i = 0; i < 4; i++) {
            float h  = tanh_fast(acc[rt][ct][i]);
            float sv = bf2f(ldsS[c * PADC + rb + i]);
            u32 zp = zpk[rt][ct][i >> 1];
            u32 gp = gpk[rt][ct][i >> 1];
            float z = bf2f((u16)((i & 1) ? (zp >> 16) : (zp & 0xffffu)));
            float g = bf2f((u16)((i & 1) ? (gp >> 16) : (gp & 0xffffu)));
            float sn = (1.0f - g) * h + z * sv;
            ldsS[c * PADC + rb + i] = f2bf(sn);
          }
        }
    }
    __syncthreads();   // publish S_next
  }

  // ---- out = W @ S3 + b : 8 threads per column, shuffle-reduce ----
  {
    int c = tid >> 3;
    int seg = tid & 7;
    const u16* s3 = &ldsS[c * PADC + seg * 64];
    float p = 0.0f;
#pragma unroll 8
    for (int r = 0; r < 64; r++) p += ldv(ka.Wout, seg * 64 + r, isbf) * bf2f(s3[r]);
    p += __shfl_xor(p, 1);
    p += __shfl_xor(p, 2);
    p += __shfl_xor(p, 4);
    if (seg == 0) {
      float res = p + ldv(ka.bout, 0, isbf);
      if (isbf) ((u16*)ka.out)[c0 + c] = f2bf(res);
      else      ((float*)ka.out)[c0 + c] = res;
    }
  }
}

extern "C" void kernel_launch(void* const* d_in, const int* in_sizes, int n_in,
                              void* d_out, int out_size, void* d_ws, size_t ws_size,
                              hipStream_t stream) {
  // setup_inputs order:
  // 0:x 1:W1 2:b1 | 3:Uz1 4:Wz1 5:bz1 | 6:Ug1 7:Wg1 8:bg1 | 9:Ur1 10:Wr1 11:br1
  // 12:Uh1 13:Wh1 14:bh1 | 15:Uz2 16:Wz2 17:bz2 | 18:Ug2 19:Wg2 20:bg2
  // 21:Ur2 22:Wr2 23:br2 | 24:Uh2 25:Wh2 26:bh2 | 27:W 28:b
  static const int widx[8] = {4, 7, 10, 13, 16, 19, 22, 25};
  static const int uidx[8] = {3, 6, 9, 12, 15, 18, 21, 24};
  static const int bidx[8] = {5, 8, 11, 14, 17, 20, 23, 26};

  u16* ws16  = (u16*)d_ws;
  u32* flagp = (u32*)(ws16 + FLAG_OFF);

  hipLaunchKernelGGL(sniff_kernel, dim3(1), dim3(64), 0, stream,
                     (const u16*)d_in[0], flagp);

  SwzArgs sa;
  for (int i = 0; i < 8; i++) sa.src[i] = d_in[widx[i]];
  sa.dst  = ws16;
  sa.flag = flagp;
  hipLaunchKernelGGL(swizzle_kernel, dim3(1024), dim3(256), 0, stream, sa);

  KArgs ka;
  ka.x  = d_in[0];
  ka.W1 = d_in[1];
  ka.b1 = d_in[2];
  for (int i = 0; i < 8; i++) {
    ka.U[i]  = d_in[uidx[i]];
    ka.Bv[i] = d_in[bidx[i]];
  }
  ka.Wout = d_in[27];
  ka.bout = d_in[28];
  ka.ws   = ws16;
  ka.flag = flagp;
  ka.out  = d_out;
  hipLaunchKernelGGL(pdenet_kernel, dim3(NCOL / NT), dim3(512), 0, stream, ka);
}